// Round 1
// baseline (140.274 us; speedup 1.0000x reference)
//
#include <hip/hip_runtime.h>

// Problem constants (fixed by setup_inputs): B=4, N=4096, K=512.
#define BB 4
#define NN 4096
#define KK 512
#define BLOCK 256
#define ROWS 16                      // rows per block -> (BB*NN)/ROWS = 1024 blocks
#define GRID ((BB * NN) / ROWS)      // 1024

static constexpr float W_P  = 1.0f;
static constexpr float W_C  = 1.0f;
static constexpr float EPSV = 1e-6f;

// Symmetric 3x3 inverse of (S + eps*I), S row-major 9 floats (S is exactly
// symmetric by construction: 0.1*L*L^T + 0.1*I). Matches reference adjugate/det.
__device__ __forceinline__ void inv3_sym(const float* __restrict__ S,
                                         float& i00, float& i01, float& i02,
                                         float& i11, float& i12, float& i22) {
    float a00 = S[0] + EPSV, a01 = S[1], a02 = S[2];
    float a11 = S[4] + EPSV, a12 = S[5];
    float a22 = S[8] + EPSV;
    float c00 = a11 * a22 - a12 * a12;
    float c01 = a02 * a12 - a01 * a22;
    float c02 = a01 * a12 - a02 * a11;
    float c11 = a00 * a22 - a02 * a02;
    float c12 = a01 * a02 - a00 * a12;
    float c22 = a00 * a11 - a01 * a01;
    float det = a00 * c00 + a01 * c01 + a02 * c02;
    float r = 1.0f / det;
    i00 = c00 * r; i01 = c01 * r; i02 = c02 * r;
    i11 = c11 * r; i12 = c12 * r; i22 = c22 * r;
}

// Fused kernel, k-quad ownership version.
//
// Each thread owns 4 consecutive parents (one "k-quad", q = tid & 127) and 8
// of the block's 16 rows (h = tid >> 7 selects the half). The parent quad's
// 36 floats are loaded from LDS ONCE into registers (9 ds_read_b128), then A
// is streamed with float4 loads (1 dwordx4 per row -> 16 B/lane coalescing).
//
// Parent LDS layout is j-plane swizzled: element k lives at index
// ((k&3)<<7)|(k>>2), so the 4 reads of a quad are each lane-stride-16B
// (conflict-free b128 with immediate offsets j*2048). i22 is quad-packed so
// the 4 values arrive in one b128. Off-diagonal inverse entries are
// pre-doubled at staging (2*x exact in fp32).
//
// Partials (no atomics, no ws-init assumption) go to part[]:
// [0..G) = sum maha_p*A*mask, [G..2G) = sum maha_c*A*mask, [2G..3G) = mask sum.
__global__ __launch_bounds__(BLOCK, 4) void main_kernel(
        const float* __restrict__ mu_c, const float* __restrict__ Sg_c,
        const float* __restrict__ mu_p, const float* __restrict__ Sg_p,
        const float* __restrict__ A,    const float* __restrict__ mask,
        float* __restrict__ part) {
    __shared__ float4 sP0[KK];       // j-plane swizzled: mu0, mu1, mu2, i00
    __shared__ float4 sP1[KK];       // j-plane swizzled: 2*i01, 2*i02, i11, 2*i12
    __shared__ float4 sP2[KK / 4];   // quad-packed i22: sP2[q] = {i22[4q..4q+3]}
    __shared__ float4 sC0[ROWS];
    __shared__ float4 sC1[ROWS];
    __shared__ float  sC2[ROWS];
    __shared__ float  sM[ROWS];
    __shared__ float  red[8];

    const int tid = threadIdx.x;
    const int rowStart = blockIdx.x * ROWS;   // global row index b*N+n
    const int b = rowStart / NN;

    // Parent staging + inversion (512 parents / 256 threads = 2 each).
    for (int k = tid; k < KK; k += BLOCK) {
        const int gp = b * KK + k;
        float i00, i01, i02, i11, i12, i22;
        inv3_sym(Sg_p + (size_t)gp * 9, i00, i01, i02, i11, i12, i22);
        const float* mu = mu_p + (size_t)gp * 3;
        const int idx = ((k & 3) << 7) | (k >> 2);
        sP0[idx] = make_float4(mu[0], mu[1], mu[2], i00);
        sP1[idx] = make_float4(2.0f * i01, 2.0f * i02, i11, 2.0f * i12);
        ((float*)sP2)[k] = i22;      // linear float = quad-packed float4
    }
    // Child staging + inversion (first 16 threads).
    if (tid < ROWS) {
        const int r = rowStart + tid;
        float i00, i01, i02, i11, i12, i22;
        inv3_sym(Sg_c + (size_t)r * 9, i00, i01, i02, i11, i12, i22);
        const float* mu = mu_c + (size_t)r * 3;
        sC0[tid] = make_float4(mu[0], mu[1], mu[2], i00);
        sC1[tid] = make_float4(2.0f * i01, 2.0f * i02, i11, 2.0f * i12);
        sC2[tid] = i22;
        sM[tid] = mask[r];
    }
    __syncthreads();

    const int q = tid & 127;         // k-quad: covers k = 4q .. 4q+3
    const int h = tid >> 7;          // row half: waves 0-1 -> rows 0-7, waves 2-3 -> 8-15

    // Parent quad -> registers, once. Conflict-free b128 (lane stride 16B).
    float4 p0[4], p1[4];
    #pragma unroll
    for (int j = 0; j < 4; ++j) {
        p0[j] = sP0[(j << 7) | q];
        p1[j] = sP1[(j << 7) | q];
    }
    const float4 p2v = sP2[q];
    const float p2a[4] = {p2v.x, p2v.y, p2v.z, p2v.w};

    float sp = 0.0f, sc = 0.0f;
    const float* __restrict__ Abase = A + (size_t)rowStart * KK + (q << 2);

    #pragma unroll
    for (int rr = 0; rr < 8; ++rr) {
        const int r = (h << 3) + rr;
        // wave-uniform LDS reads -> broadcast, no conflicts
        const float4 cA = sC0[r];
        const float4 cB = sC1[r];
        const float  cC = sC2[r];
        const float  m  = sM[r];
        const float4 av = *reinterpret_cast<const float4*>(Abase + (size_t)r * KK);
        const float aa[4] = {av.x * m, av.y * m, av.z * m, av.w * m};
        #pragma unroll
        for (int j = 0; j < 4; ++j) {
            const float d0 = cA.x - p0[j].x;
            const float d1 = cA.y - p0[j].y;
            const float d2 = cA.z - p0[j].z;
            const float e00 = d0 * d0, e11 = d1 * d1, e22 = d2 * d2;
            const float e01 = d0 * d1, e02 = d0 * d2, e12 = d1 * d2;
            const float qp = p0[j].w * e00 + p1[j].z * e11 + p2a[j] * e22
                           + p1[j].x * e01 + p1[j].y * e02 + p1[j].w * e12;
            const float qc = cA.w * e00 + cB.z * e11 + cC * e22
                           + cB.x * e01 + cB.y * e02 + cB.w * e12;
            sp += qp * aa[j];
            sc += qc * aa[j];
        }
    }

    // Block reduction: wave-64 shuffle, then cross-wave via LDS.
    #pragma unroll
    for (int off = 32; off > 0; off >>= 1) {
        sp += __shfl_down(sp, off);
        sc += __shfl_down(sc, off);
    }
    const int wave = tid >> 6;
    if ((tid & 63) == 0) { red[wave * 2] = sp; red[wave * 2 + 1] = sc; }
    __syncthreads();
    if (tid == 0) {
        part[blockIdx.x]            = red[0] + red[2] + red[4] + red[6];
        part[GRID + blockIdx.x]     = red[1] + red[3] + red[5] + red[7];
        float msum = 0.0f;
        #pragma unroll
        for (int i = 0; i < ROWS; ++i) msum += sM[i];
        part[2 * GRID + blockIdx.x] = msum;
    }
}

// Reduce the 3*GRID partials and write the 3 outputs.
__global__ __launch_bounds__(256) void finalize_kernel(
        const float* __restrict__ part, float* __restrict__ out) {
    __shared__ float red[12];
    const int tid = threadIdx.x;
    float tp = 0.0f, tc = 0.0f, tm = 0.0f;
    for (int i = tid; i < GRID; i += 256) {
        tp += part[i];
        tc += part[GRID + i];
        tm += part[2 * GRID + i];
    }
    #pragma unroll
    for (int off = 32; off > 0; off >>= 1) {
        tp += __shfl_down(tp, off);
        tc += __shfl_down(tc, off);
        tm += __shfl_down(tm, off);
    }
    const int wave = tid >> 6;
    if ((tid & 63) == 0) {
        red[wave * 3] = tp; red[wave * 3 + 1] = tc; red[wave * 3 + 2] = tm;
    }
    __syncthreads();
    if (tid == 0) {
        float sp = red[0] + red[3] + red[6] + red[9];
        float sc = red[1] + red[4] + red[7] + red[10];
        float sm = red[2] + red[5] + red[8] + red[11];
        float denom = fmaxf(sm, 1.0f);
        out[0] = (W_P * sp + W_C * sc) / denom;
        out[1] = sp / denom;
        out[2] = sc / denom;
    }
}

extern "C" void kernel_launch(void* const* d_in, const int* in_sizes, int n_in,
                              void* d_out, int out_size, void* d_ws, size_t ws_size,
                              hipStream_t stream) {
    const float* mu_c = (const float*)d_in[0];
    const float* Sg_c = (const float*)d_in[1];
    const float* mu_p = (const float*)d_in[2];
    const float* Sg_p = (const float*)d_in[3];
    const float* A    = (const float*)d_in[4];
    const float* mask = (const float*)d_in[5];
    float* out  = (float*)d_out;
    float* part = (float*)d_ws;   // 3*GRID floats, all written by main_kernel

    main_kernel<<<GRID, BLOCK, 0, stream>>>(mu_c, Sg_c, mu_p, Sg_p, A, mask, part);
    finalize_kernel<<<1, 256, 0, stream>>>(part, out);
}

// Round 2
// 96.007 us; speedup vs baseline: 1.4611x; 1.4611x over previous
//
#include <hip/hip_runtime.h>

// Problem constants (fixed by setup_inputs): B=4, N=4096, K=512.
#define BB 4
#define NN 4096
#define KK 512
#define BLOCK 256
#define ROWS 16                      // rows per block -> (BB*NN)/ROWS = 1024 blocks
#define GRID ((BB * NN) / ROWS)      // 1024

static constexpr float W_P  = 1.0f;
static constexpr float W_C  = 1.0f;
static constexpr float EPSV = 1e-6f;

// Symmetric 3x3 inverse of (S + eps*I), S row-major 9 floats (S is exactly
// symmetric by construction: 0.1*L*L^T + 0.1*I). Matches reference adjugate/det.
__device__ __forceinline__ void inv3_sym(const float* __restrict__ S,
                                         float& i00, float& i01, float& i02,
                                         float& i11, float& i12, float& i22) {
    float a00 = S[0] + EPSV, a01 = S[1], a02 = S[2];
    float a11 = S[4] + EPSV, a12 = S[5];
    float a22 = S[8] + EPSV;
    float c00 = a11 * a22 - a12 * a12;
    float c01 = a02 * a12 - a01 * a22;
    float c02 = a01 * a12 - a02 * a11;
    float c11 = a00 * a22 - a02 * a02;
    float c12 = a01 * a02 - a00 * a12;
    float c22 = a00 * a11 - a01 * a01;
    float det = a00 * c00 + a01 * c01 + a02 * c02;
    float r = 1.0f / det;
    i00 = c00 * r; i01 = c01 * r; i02 = c02 * r;
    i11 = c11 * r; i12 = c12 * r; i22 = c22 * r;
}

// Fused kernel: per block, compute the batch's 512 parent inverses into LDS
// (cheap: ~25 KB of L2-resident reads, ~70 VALU ops/thread) and the block's 16
// child inverses into LDS, then stream A once. Off-diagonal inverse entries are
// pre-doubled at staging (2*x is exact in fp32) to save a multiply per element.
// Each thread handles 2 rows per parent-LDS fetch. Partials (no atomics, no
// init needed) go to part[] : [0..GRID) = sum maha_p*A*mask, [GRID..2G) =
// sum maha_c*A*mask, [2G..3G) = block mask sum.
__global__ __launch_bounds__(BLOCK) void main_kernel(
        const float* __restrict__ mu_c, const float* __restrict__ Sg_c,
        const float* __restrict__ mu_p, const float* __restrict__ Sg_p,
        const float* __restrict__ A,    const float* __restrict__ mask,
        float* __restrict__ part) {
    __shared__ float4 sP0[KK];     // mu0, mu1, mu2, i00
    __shared__ float4 sP1[KK];     // 2*i01, 2*i02, i11, 2*i12
    __shared__ float  sP2[KK];     // i22
    __shared__ float4 sC0[ROWS];
    __shared__ float4 sC1[ROWS];
    __shared__ float  sC2[ROWS];
    __shared__ float  sM[ROWS];
    __shared__ float  red[8];

    const int tid = threadIdx.x;
    const int rowStart = blockIdx.x * ROWS;   // global row index b*N+n
    const int b = rowStart / NN;

    // Parent staging + inversion (512 parents / 256 threads = 2 each).
    for (int k = tid; k < KK; k += BLOCK) {
        const int gp = b * KK + k;
        float i00, i01, i02, i11, i12, i22;
        inv3_sym(Sg_p + (size_t)gp * 9, i00, i01, i02, i11, i12, i22);
        const float* mu = mu_p + (size_t)gp * 3;
        sP0[k] = make_float4(mu[0], mu[1], mu[2], i00);
        sP1[k] = make_float4(2.0f * i01, 2.0f * i02, i11, 2.0f * i12);
        sP2[k] = i22;
    }
    // Child staging + inversion (first 16 threads).
    if (tid < ROWS) {
        const int r = rowStart + tid;
        float i00, i01, i02, i11, i12, i22;
        inv3_sym(Sg_c + (size_t)r * 9, i00, i01, i02, i11, i12, i22);
        const float* mu = mu_c + (size_t)r * 3;
        sC0[tid] = make_float4(mu[0], mu[1], mu[2], i00);
        sC1[tid] = make_float4(2.0f * i01, 2.0f * i02, i11, 2.0f * i12);
        sC2[tid] = i22;
        sM[tid] = mask[r];
    }
    __syncthreads();

    float sp = 0.0f, sc = 0.0f;

    for (int rg = 0; rg < ROWS; rg += 2) {
        // wave-uniform LDS reads -> broadcast, no conflicts
        const float4 c0A = sC0[rg],     c0B = sC1[rg];
        const float  c0C = sC2[rg],     m0  = sM[rg];
        const float4 c1A = sC0[rg + 1], c1B = sC1[rg + 1];
        const float  c1C = sC2[rg + 1], m1  = sM[rg + 1];
        const float* __restrict__ A0 = A + (size_t)(rowStart + rg) * KK;
        const float* __restrict__ A1 = A0 + KK;

        #pragma unroll
        for (int ko = 0; ko < KK; ko += BLOCK) {
            const int k = ko + tid;
            const float4 p0 = sP0[k];
            const float4 p1 = sP1[k];
            const float  p2 = sP2[k];
            const float a0 = A0[k] * m0;
            const float a1 = A1[k] * m1;
            {   // row 0
                float d0 = c0A.x - p0.x, d1 = c0A.y - p0.y, d2 = c0A.z - p0.z;
                float e00 = d0 * d0, e11 = d1 * d1, e22 = d2 * d2;
                float e01 = d0 * d1, e02 = d0 * d2, e12 = d1 * d2;
                float qp = p0.w * e00 + p1.z * e11 + p2 * e22
                         + p1.x * e01 + p1.y * e02 + p1.w * e12;
                float qc = c0A.w * e00 + c0B.z * e11 + c0C * e22
                         + c0B.x * e01 + c0B.y * e02 + c0B.w * e12;
                sp += qp * a0;
                sc += qc * a0;
            }
            {   // row 1
                float d0 = c1A.x - p0.x, d1 = c1A.y - p0.y, d2 = c1A.z - p0.z;
                float e00 = d0 * d0, e11 = d1 * d1, e22 = d2 * d2;
                float e01 = d0 * d1, e02 = d0 * d2, e12 = d1 * d2;
                float qp = p0.w * e00 + p1.z * e11 + p2 * e22
                         + p1.x * e01 + p1.y * e02 + p1.w * e12;
                float qc = c1A.w * e00 + c1B.z * e11 + c1C * e22
                         + c1B.x * e01 + c1B.y * e02 + c1B.w * e12;
                sp += qp * a1;
                sc += qc * a1;
            }
        }
    }

    // Block reduction: wave-64 shuffle, then cross-wave via LDS.
    #pragma unroll
    for (int off = 32; off > 0; off >>= 1) {
        sp += __shfl_down(sp, off);
        sc += __shfl_down(sc, off);
    }
    const int wave = tid >> 6;
    if ((tid & 63) == 0) { red[wave * 2] = sp; red[wave * 2 + 1] = sc; }
    __syncthreads();
    if (tid == 0) {
        part[blockIdx.x]            = red[0] + red[2] + red[4] + red[6];
        part[GRID + blockIdx.x]     = red[1] + red[3] + red[5] + red[7];
        float msum = 0.0f;
        #pragma unroll
        for (int i = 0; i < ROWS; ++i) msum += sM[i];
        part[2 * GRID + blockIdx.x] = msum;
    }
}

// Reduce the 3*GRID partials and write the 3 outputs.
__global__ __launch_bounds__(256) void finalize_kernel(
        const float* __restrict__ part, float* __restrict__ out) {
    __shared__ float red[12];
    const int tid = threadIdx.x;
    float tp = 0.0f, tc = 0.0f, tm = 0.0f;
    for (int i = tid; i < GRID; i += 256) {
        tp += part[i];
        tc += part[GRID + i];
        tm += part[2 * GRID + i];
    }
    #pragma unroll
    for (int off = 32; off > 0; off >>= 1) {
        tp += __shfl_down(tp, off);
        tc += __shfl_down(tc, off);
        tm += __shfl_down(tm, off);
    }
    const int wave = tid >> 6;
    if ((tid & 63) == 0) {
        red[wave * 3] = tp; red[wave * 3 + 1] = tc; red[wave * 3 + 2] = tm;
    }
    __syncthreads();
    if (tid == 0) {
        float sp = red[0] + red[3] + red[6] + red[9];
        float sc = red[1] + red[4] + red[7] + red[10];
        float sm = red[2] + red[5] + red[8] + red[11];
        float denom = fmaxf(sm, 1.0f);
        out[0] = (W_P * sp + W_C * sc) / denom;
        out[1] = sp / denom;
        out[2] = sc / denom;
    }
}

extern "C" void kernel_launch(void* const* d_in, const int* in_sizes, int n_in,
                              void* d_out, int out_size, void* d_ws, size_t ws_size,
                              hipStream_t stream) {
    const float* mu_c = (const float*)d_in[0];
    const float* Sg_c = (const float*)d_in[1];
    const float* mu_p = (const float*)d_in[2];
    const float* Sg_p = (const float*)d_in[3];
    const float* A    = (const float*)d_in[4];
    const float* mask = (const float*)d_in[5];
    float* out  = (float*)d_out;
    float* part = (float*)d_ws;   // 3*GRID floats, all written by main_kernel

    main_kernel<<<GRID, BLOCK, 0, stream>>>(mu_c, Sg_c, mu_p, Sg_p, A, mask, part);
    finalize_kernel<<<1, 256, 0, stream>>>(part, out);
}